// Round 4
// baseline (505.768 us; speedup 1.0000x reference)
//
#include <hip/hip_runtime.h>
#include <stdint.h>

// Quanvolution + linear(784->10) + log_softmax, B=65536, fp32.
// R3: async global_load_lds double-buffered panels + counted-vmcnt pipeline,
//     XOR-swizzled LDS (swizzle applied to SOURCE addr, linear dest),
//     W via per-lane vector loads (L1-resident), raw s_barrier (no drains).
//
// Geometry: 2048 blocks x 256 thr (4 waves). Block owns 32 rows.
// Wave w <-> patch-row segment: w0:[0,4) w1:[4,8) w2:[8,11) w3:[11,14).
// Lane: r = lane&31 (row), hf = lane>>5 (7 patches each half of patch-row).
// Panel: [4 seg][32 row][16 quads(16B)] = 32 KB, double buffered = 64 KB LDS.
// Row layout: quads 0..6 = top 28 floats, 7..13 = bottom 28, 14..15 dup-pad.
// Swizzle: data for (r,q) lives at LDS slot r*16 + (q ^ (r&15)).

typedef __attribute__((address_space(1))) const void GAS;
typedef __attribute__((address_space(3))) void LAS;

__device__ __forceinline__ void gl_lds16(const void* g, void* l) {
    __builtin_amdgcn_global_load_lds((GAS*)g, (LAS*)l, 16, 0, 0);
}

#define WAITV(N) do { asm volatile("s_waitcnt vmcnt(" #N ")" ::: "memory"); \
                      __builtin_amdgcn_sched_barrier(0); } while (0)
#define WAITL    do { asm volatile("s_waitcnt lgkmcnt(0)" ::: "memory"); \
                      __builtin_amdgcn_sched_barrier(0); } while (0)
#define BAR      __builtin_amdgcn_s_barrier()

__global__ __launch_bounds__(256, 2)
void quanv_fused4_kernel(const float* __restrict__ x,
                         const float* __restrict__ Wm,
                         const float* __restrict__ bias,
                         float* __restrict__ out) {
    __shared__ float sm[16384];   // 65536 B = 2 x 32KB panel buffers

    const int t    = threadIdx.x;
    const int lane = t & 63;
    const int w    = t >> 6;          // wave id (wave-uniform value)
    const int r    = lane & 31;       // my row
    const int hf   = lane >> 5;       // half of the patch-row
    const int rx   = r & 15;
    const int R0   = blockIdx.x * 32;
    const float* xb = x + (size_t)R0 * 784;

    float acc[10];
#pragma unroll
    for (int k = 0; k < 10; ++k) acc[k] = 0.f;

    // ---- staging: wave stages `nch` 1KB chunks into buffer `buf` for
    //      iteration `tt`. chunk c -> seg c>>3, granule g = c*64+lane.
    auto STAGE = [&](int buf, int tt, int nch) {
#pragma unroll
        for (int j = 0; j < 8; ++j) {
            if (j >= nch) break;
            const int c   = w * nch + j;
            const int seg = c >> 3;
            const int pr  = (seg < 2 ? 4 * seg : 3 * seg + 2) + tt;
            const int rr  = (4 * c + (lane >> 4)) & 31;      // row of my granule
            int q = (lane & 15) ^ (rr & 15);                 // source-side swizzle
            q = q > 13 ? 13 : q;                             // dup-pad granules
            const float* src = xb + rr * 784 + pr * 56 + 4 * q;
            const uint32_t ub = __builtin_amdgcn_readfirstlane(
                (uint32_t)(buf * 32768 + c * 1024));
            gl_lds16(src, (char*)sm + ub);
        }
    };

    // ---- compute: my wave's patch-row `pr` from buffer `buf` ----
    auto COMPUTE = [&](int buf, int pr) {
        const char* base = (const char*)sm + buf * 32768 + w * 8192 + r * 256;
#pragma unroll
        for (int pj7 = 0; pj7 < 7; ++pj7) {
            const int pj  = hf * 7 + pj7;
            const int qt  = pj >> 1;                 // top quad 0..6
            const int sub = (pj & 1) * 8;
            const float2 a  = *(const float2*)(base + ((qt       ^ rx) << 4) + sub);
            const float2 bq = *(const float2*)(base + (((qt + 7) ^ rx) << 4) + sub);
            const float c0 = __cosf(a.x),  c1 = __cosf(a.y);
            const float c2 = __cosf(bq.x), c3 = __cosf(bq.y);
            const float f0 = c0 + a.x;
            const float f1 = c0 * c1 + a.y;
            const float f2 = c2 + bq.x;
            const float f3 = c2 * c3 + bq.y;
            // per-lane (hf-divergent) -> vector loads through L1, broadcast
            const float* wp = Wm + (pr * 14 + pj) * 4;
#pragma unroll
            for (int k = 0; k < 10; ++k) {
                const float4 wv = *(const float4*)(wp + (size_t)k * 784);
                acc[k] = fmaf(f0, wv.x, fmaf(f1, wv.y,
                         fmaf(f2, wv.z, fmaf(f3, wv.w, acc[k]))));
            }
        }
    };

    const int pr0w = (w < 2 ? 4 * w : 3 * w + 2);

    // ---- pipelined main loop: 4 iterations, loads never drained mid-loop ----
    STAGE(0, 0, 8);
    STAGE(1, 1, 8);

    WAITV(8); BAR;                 // buf0 landed (newest 8 = tt1 still inflight)
    COMPUTE(0, pr0w + 0);
    WAITL; BAR;                    // everyone done reading buf0
    STAGE(0, 2, 8);

    WAITV(8); BAR;                 // buf1 landed
    COMPUTE(1, pr0w + 1);
    WAITL; BAR;
    STAGE(1, 3, 4);                // ragged tail: segs 0,1 only

    WAITV(4); BAR;                 // buf0(tt2) landed
    COMPUTE(0, pr0w + 2);
    WAITL; BAR;

    WAITV(0); BAR;                 // buf1(tt3) landed
    if (w < 2) COMPUTE(1, pr0w + 3);
    WAITL; BAR;

    // ---- reduction: hf pair via shuffle, waves via LDS (reuse sm) ----
#pragma unroll
    for (int k = 0; k < 10; ++k) acc[k] += __shfl_xor(acc[k], 32, 64);

    float* part = sm;
    if (w > 0 && hf == 0) {
#pragma unroll
        for (int k = 0; k < 10; ++k) part[((w - 1) * 32 + r) * 10 + k] = acc[k];
    }
    __syncthreads();
    if (w == 0 && hf == 0) {
#pragma unroll
        for (int s = 0; s < 3; ++s)
#pragma unroll
            for (int k = 0; k < 10; ++k) acc[k] += part[(s * 32 + r) * 10 + k];

        float mx = -1e30f;
#pragma unroll
        for (int k = 0; k < 10; ++k) { acc[k] += bias[k]; mx = fmaxf(mx, acc[k]); }
        float sum = 0.f;
#pragma unroll
        for (int k = 0; k < 10; ++k) sum += __expf(acc[k] - mx);
        const float ls = __logf(sum) + mx;

        float* o = out + (size_t)(R0 + r) * 10;
#pragma unroll
        for (int k = 0; k < 10; k += 2)
            *(float2*)(o + k) = make_float2(acc[k] - ls, acc[k + 1] - ls);
    }
}

extern "C" void kernel_launch(void* const* d_in, const int* in_sizes, int n_in,
                              void* d_out, int out_size, void* d_ws, size_t ws_size,
                              hipStream_t stream) {
    const float* x    = (const float*)d_in[0];   // [65536, 784]
    const float* Wm   = (const float*)d_in[1];   // [10, 784]
    const float* bias = (const float*)d_in[2];   // [10]
    float* out        = (float*)d_out;           // [65536, 10]

    quanv_fused4_kernel<<<dim3(2048), dim3(256), 0, stream>>>(x, Wm, bias, out);
}

// Round 5
// 94.925 us; speedup vs baseline: 5.3281x; 5.3281x over previous
//
#include <hip/hip_runtime.h>

// Quanvolution + linear(784->10) + log_softmax, B=65536, fp32.
// R4: zero-LDS, zero-barrier, pure-register design.
//  - 1024 blocks x 256 thr; 4 independent waves/block; wave owns 16 rows.
//  - lane = (q, r): q = lane>>4 (patch quarter), r = lane&15 (row).
//    Quarter q handles patches {0..3 / 4..7 / 8..10 / 11..13} of each
//    patch-row tt: lane reads its own 8+8 contiguous floats as float2s.
//    Per wave-iter the 16 rows' 224B regions are fully consumed through
//    L1 within a short window -> granule-clean like R0's staging,
//    without LDS/barriers/waitcnts.
//  - W: 4 distinct addresses per wave instr (quarter-major lanes) ->
//    broadcast float4 loads, W (31KB) L1-resident.
//  - quarter reduction via __shfl_xor(16/32); q==0 lanes do softmax+store.
//  - occupancy 16 waves/CU (4/SIMD), 2x R0; no LDS -> no conflicts.

__global__ __launch_bounds__(256, 4)
void quanv_fused5_kernel(const float* __restrict__ x,
                         const float* __restrict__ Wm,
                         const float* __restrict__ bias,
                         float* __restrict__ out) {
    const int t    = threadIdx.x;
    const int lane = t & 63;
    const int w    = t >> 6;          // wave id, waves fully independent
    const int q    = lane >> 4;       // quarter 0..3
    const int r    = lane & 15;       // row within wave
    const int row  = blockIdx.x * 64 + w * 16 + r;
    const float* xr = x + (size_t)row * 784;

    const int pb  = (q < 2) ? 4 * q : 3 * q + 2;   // patch base {0,4,8,11}
    const int cnt = (q < 2) ? 4 : 3;               // patches this lane owns

    float acc[10];
#pragma unroll
    for (int k = 0; k < 10; ++k) acc[k] = 0.f;

#pragma unroll 2
    for (int tt = 0; tt < 14; ++tt) {
        const float* base = xr + tt * 56 + 2 * pb;   // my top pairs
        // top pairs of my patches (floats 2pb..2pb+7), bottom at +28
        float2 tp[4], bp[4];
        tp[0] = *(const float2*)(base + 0);
        tp[1] = *(const float2*)(base + 2);
        tp[2] = *(const float2*)(base + 4);
        bp[0] = *(const float2*)(base + 28);
        bp[1] = *(const float2*)(base + 30);
        bp[2] = *(const float2*)(base + 32);
        if (q < 2) {   // 4th patch exists only for quarters 0,1 (avoids OOB)
            tp[3] = *(const float2*)(base + 6);
            bp[3] = *(const float2*)(base + 34);
        } else {
            tp[3] = make_float2(0.f, 0.f);
            bp[3] = make_float2(0.f, 0.f);
        }

        const float* wrow = Wm + (tt * 14 + pb) * 4;
#pragma unroll
        for (int j = 0; j < 4; ++j) {
            if (j < cnt) {
                const float p0 = tp[j].x, p1 = tp[j].y;
                const float p2 = bp[j].x, p3 = bp[j].y;
                const float c0 = __cosf(p0), c1 = __cosf(p1);
                const float c2 = __cosf(p2), c3 = __cosf(p3);
                const float f0 = c0 + p0;
                const float f1 = c0 * c1 + p1;
                const float f2 = c2 + p2;
                const float f3 = c2 * c3 + p3;
                const float* wp = wrow + 4 * j;   // 4 distinct addrs per wave
#pragma unroll
                for (int k = 0; k < 10; ++k) {
                    const float4 wv = *(const float4*)(wp + (size_t)k * 784);
                    acc[k] = fmaf(f0, wv.x, fmaf(f1, wv.y,
                             fmaf(f2, wv.z, fmaf(f3, wv.w, acc[k]))));
                }
            }
        }
    }

    // ---- quarter reduction (in-register, no LDS) ----
#pragma unroll
    for (int k = 0; k < 10; ++k) {
        acc[k] += __shfl_xor(acc[k], 16, 64);
        acc[k] += __shfl_xor(acc[k], 32, 64);
    }

    if (q == 0) {
        float mx = -1e30f;
#pragma unroll
        for (int k = 0; k < 10; ++k) { acc[k] += bias[k]; mx = fmaxf(mx, acc[k]); }
        float sum = 0.f;
#pragma unroll
        for (int k = 0; k < 10; ++k) sum += __expf(acc[k] - mx);
        const float ls = __logf(sum) + mx;

        float* o = out + (size_t)row * 10;
#pragma unroll
        for (int k = 0; k < 10; k += 2)
            *(float2*)(o + k) = make_float2(acc[k] - ls, acc[k + 1] - ls);
    }
}

extern "C" void kernel_launch(void* const* d_in, const int* in_sizes, int n_in,
                              void* d_out, int out_size, void* d_ws, size_t ws_size,
                              hipStream_t stream) {
    const float* x    = (const float*)d_in[0];   // [65536, 784]
    const float* Wm   = (const float*)d_in[1];   // [10, 784]
    const float* bias = (const float*)d_in[2];   // [10]
    float* out        = (float*)d_out;           // [65536, 10]

    quanv_fused5_kernel<<<dim3(1024), dim3(256), 0, stream>>>(x, Wm, bias, out);
}

// Round 6
// 53.342 us; speedup vs baseline: 9.4816x; 1.7796x over previous
//
#include <hip/hip_runtime.h>
#include <hip/hip_bf16.h>
#include <stdint.h>

// Quanvolution + linear(784->10) + log_softmax via MFMA, B=65536, fp32 in/out.
// R5: feats@W.T as mfma_f32_16x16x32_bf16. Wave = 16 rows. Lane (r16,kg)
// computes features for 2 patches per K-block entirely in registers.
// K is PERMUTED (allowed: contraction is k-order invariant as long as W is
// permuted identically): each patch-row owns 64 K-slots (56 real + 8 pad),
// so per K-block pr/h are compile-time and x-loads use immediate offsets.
// Pre-kernel bakes W into bf16 [16][896] (28 KB) in d_ws: permuted, zero
// for pad slots and rows n>=10 -> pad-lane garbage features hit W=0.
// Main kernel: NO LDS, NO barriers. Epilogue: shuffle-butterfly log_softmax.

typedef __attribute__((ext_vector_type(8))) short short8;
typedef __attribute__((ext_vector_type(4))) float f32x4;

// ---- pre-kernel: ws16[n][kp], n<16, kp<896, stride 896 bf16 (1792 B) ----
// kp = 32*kb + 8*kg + e ; kb = 2*pr+h ; pc = h*7 + 2*kg + (e>>2)
// col = (pr*14+pc)*4 + (e&3) ; value 0 unless n<10 && (kg<3 || e<4)
__global__ void quanv_wprep_kernel(const float* __restrict__ Wm,
                                   uint32_t* __restrict__ ws) {
    const int idx = blockIdx.x * 256 + threadIdx.x;   // [0, 7168)
    if (idx >= 16 * 448) return;
    const int n  = idx / 448;
    const int kk = idx - n * 448;     // u32 slot; holds kp=2kk, 2kk+1
    uint32_t outv = 0;
    if (n < 10) {
        const int kp = 2 * kk;
        const int kb = kp >> 5, r5 = kp & 31, kg = r5 >> 3, e0 = r5 & 7;
        const int pr = kb >> 1, h = kb & 1;
        uint32_t halves[2];
#pragma unroll
        for (int d = 0; d < 2; ++d) {
            const int e = e0 + d;                  // same kb,kg for both
            const int pc = h * 7 + 2 * kg + (e >> 2);
            float v = 0.f;
            if (kg < 3 || e < 4) v = Wm[n * 784 + (pr * 14 + pc) * 4 + (e & 3)];
            halves[d] = (uint32_t)__bfloat16_as_ushort(__float2bfloat16(v));
        }
        outv = halves[0] | (halves[1] << 16);
    }
    ws[idx] = outv;
}

// ---- main kernel ----
__global__ __launch_bounds__(256, 4)
void quanv_mfma_kernel(const float* __restrict__ x,
                       const char* __restrict__ wsb,   // bf16 W [16][896]
                       const float* __restrict__ bias,
                       float* __restrict__ out) {
    const int t   = threadIdx.x;
    const int l   = t & 63;
    const int w   = t >> 6;
    const int r16 = l & 15;        // A-row (x row) and B-col (class) index
    const int kg  = l >> 4;        // k-group 0..3
    const int rowBase = blockIdx.x * 64 + w * 16;
    const float* xr = x + (size_t)(rowBase + r16) * 784;

    // 3 base pointers; every load in the K-loop is an immediate offset.
    const float* xT  = xr + 4 * kg;            // top pairs (float4, 16B align)
    const float* xBa = xr + 4 * kg + 28;       // patchA bottom pair (8B align)
    const float* xBb = (kg < 3) ? (xr + 4 * kg + 30) : xr;  // patchB bottom
    const char*  wb  = wsb + 1792 * r16 + 16 * kg;          // B-frag base

    f32x4 acc = {0.f, 0.f, 0.f, 0.f};

#pragma unroll
    for (int kb = 0; kb < 28; ++kb) {
        const int pr = kb >> 1, h = kb & 1;    // compile-time per iteration
        const int off = pr * 56 + 14 * h;      // float offset (imm in bytes)
        const float4 T  = *(const float4*)(xT  + off);
        const float2 bA = *(const float2*)(xBa + off);
        const float2 bB = *(const float2*)(xBb + off);

        float f[8];
        {   // patch A: pc = h*7 + 2*kg   (always real)
            const float p0 = T.x, p1 = T.y, p2 = bA.x, p3 = bA.y;
            const float c0 = __cosf(p0), c1 = __cosf(p1);
            const float c2 = __cosf(p2), c3 = __cosf(p3);
            f[0] = c0 + p0; f[1] = c0 * c1 + p1;
            f[2] = c2 + p2; f[3] = c2 * c3 + p3;
        }
        {   // patch B: pc+1 (pad for kg==3 -> multiplied by W=0)
            const float p0 = T.z, p1 = T.w, p2 = bB.x, p3 = bB.y;
            const float c0 = __cosf(p0), c1 = __cosf(p1);
            const float c2 = __cosf(p2), c3 = __cosf(p3);
            f[4] = c0 + p0; f[5] = c0 * c1 + p1;
            f[6] = c2 + p2; f[7] = c2 * c3 + p3;
        }

        short8 a;
#pragma unroll
        for (int e = 0; e < 8; ++e)
            a[e] = (short)__bfloat16_as_ushort(__float2bfloat16(f[e]));

        const short8 b = *(const short8*)(wb + 64 * kb);
        acc = __builtin_amdgcn_mfma_f32_16x16x32_bf16(a, b, acc, 0, 0, 0);
    }

    // ---- epilogue: lane holds D[m=4*kg+j][n=r16]; log_softmax over n ----
    const float bn = bias[r16 < 10 ? r16 : 0];
#pragma unroll
    for (int j = 0; j < 4; ++j) {
        float v = (r16 < 10) ? (acc[j] + bn) : -1e30f;
        float mx = v;
        mx = fmaxf(mx, __shfl_xor(mx, 1, 64));
        mx = fmaxf(mx, __shfl_xor(mx, 2, 64));
        mx = fmaxf(mx, __shfl_xor(mx, 4, 64));
        mx = fmaxf(mx, __shfl_xor(mx, 8, 64));
        float e = (r16 < 10) ? __expf(v - mx) : 0.f;
        float s = e;
        s += __shfl_xor(s, 1, 64);
        s += __shfl_xor(s, 2, 64);
        s += __shfl_xor(s, 4, 64);
        s += __shfl_xor(s, 8, 64);
        const float ls = __logf(s) + mx;
        if (r16 < 10)
            out[(size_t)(rowBase + 4 * kg + j) * 10 + r16] = v - ls;
    }
}

extern "C" void kernel_launch(void* const* d_in, const int* in_sizes, int n_in,
                              void* d_out, int out_size, void* d_ws, size_t ws_size,
                              hipStream_t stream) {
    const float* x    = (const float*)d_in[0];   // [65536, 784]
    const float* Wm   = (const float*)d_in[1];   // [10, 784]
    const float* bias = (const float*)d_in[2];   // [10]
    float* out        = (float*)d_out;           // [65536, 10]

    quanv_wprep_kernel<<<dim3(28), dim3(256), 0, stream>>>(
        Wm, (uint32_t*)d_ws);
    quanv_mfma_kernel<<<dim3(1024), dim3(256), 0, stream>>>(
        x, (const char*)d_ws, bias, out);
}